// Round 1
// baseline (365.255 us; speedup 1.0000x reference)
//
#include <hip/hip_runtime.h>

#define BATCH 256
#define NNODE 512

__global__ void init_out_kernel(const float* __restrict__ b2, float* __restrict__ out) {
    int i = blockIdx.x * blockDim.x + threadIdx.x;
    if (i < BATCH) out[i] = (float)NNODE * b2[0];
}

// grid: BATCH*8 blocks, 256 threads. Block (b, chunk) handles rows [chunk*64, chunk*64+64).
// Wave layout: 4 rows in flight (sub = lane>>4), 16 lanes per row (l = lane&15),
// each lane reads 8 float4 at stride 16 -> 256B contiguous per quarter-wave.
__global__ __launch_bounds__(256) void gcn_main_kernel(
    const float* __restrict__ x,    // [B,N,2]
    const float* __restrict__ adj,  // [B,N,N]
    const float* __restrict__ W1,   // [2,4]
    const float* __restrict__ b1,   // [4]
    const float* __restrict__ W2,   // [4,1]
    float* __restrict__ out)        // [B]
{
    __shared__ __align__(16) float sx0[NNODE];
    __shared__ __align__(16) float sx1[NNODE];
    __shared__ float swsum[4];

    const int b     = blockIdx.x >> 3;
    const int chunk = blockIdx.x & 7;
    const int t     = threadIdx.x;

    // Stage node features: 1024 floats = 256 float4, deinterleave [m][2] -> x0[],x1[]
    {
        const float4 v = ((const float4*)(x + (size_t)b * NNODE * 2))[t];
        const int m = 2 * t;
        sx0[m]     = v.x; sx1[m]     = v.y;
        sx0[m + 1] = v.z; sx1[m + 1] = v.w;
    }

    // Uniform weights into registers (L2-cached scalar-ish loads, one-time)
    float w1[8], bb1[4], w2[4];
#pragma unroll
    for (int j = 0; j < 8; ++j) w1[j] = W1[j];
#pragma unroll
    for (int j = 0; j < 4; ++j) { bb1[j] = b1[j]; w2[j] = W2[j]; }

    __syncthreads();

    const int wave = t >> 6;
    const int lane = t & 63;
    const int sub  = lane >> 4;   // row within 4-row group
    const int l    = lane & 15;   // column chunk

    float acc = 0.0f;
    const int row_base = chunk * 64 + wave * 16;

#pragma unroll 1
    for (int it = 0; it < 4; ++it) {
        const int n = row_base + it * 4 + sub;
        const float4* __restrict__ arow =
            (const float4*)(adj + ((size_t)b * NNODE + n) * NNODE);

        float a0 = 0.0f, a1 = 0.0f;
#pragma unroll
        for (int k = 0; k < 8; ++k) {
            const int c = l + k * 16;                 // float4 index within row
            const float4 av  = arow[c];
            const float4 xv0 = ((const float4*)sx0)[c];
            const float4 xv1 = ((const float4*)sx1)[c];
            a0 += av.x * xv0.x + av.y * xv0.y + av.z * xv0.z + av.w * xv0.w;
            a1 += av.x * xv1.x + av.y * xv1.y + av.z * xv1.z + av.w * xv1.w;
        }

        // Reduce dot products across the 16 lanes of this row group
#pragma unroll
        for (int m = 1; m < 16; m <<= 1) {
            a0 += __shfl_xor(a0, m, 64);
            a1 += __shfl_xor(a1, m, 64);
        }

        // Tiny MLP: h = relu(agg @ W1 + b1); p = h @ W2  (b2 folded into init)
        float p = 0.0f;
#pragma unroll
        for (int j = 0; j < 4; ++j) {
            float h = a0 * w1[j] + a1 * w1[4 + j] + bb1[j];
            h = fmaxf(h, 0.0f);
            p += h * w2[j];
        }
        if (l == 0) acc += p;   // one representative lane per row group
    }

    // Wave-level then block-level reduction, one atomic per block
#pragma unroll
    for (int m = 1; m < 64; m <<= 1) acc += __shfl_xor(acc, m, 64);
    if (lane == 0) swsum[wave] = acc;
    __syncthreads();
    if (t == 0) {
        atomicAdd(out + b, swsum[0] + swsum[1] + swsum[2] + swsum[3]);
    }
}

extern "C" void kernel_launch(void* const* d_in, const int* in_sizes, int n_in,
                              void* d_out, int out_size, void* d_ws, size_t ws_size,
                              hipStream_t stream) {
    const float* x   = (const float*)d_in[0];
    const float* adj = (const float*)d_in[1];
    const float* W1  = (const float*)d_in[2];
    const float* b1  = (const float*)d_in[3];
    const float* W2  = (const float*)d_in[4];
    const float* b2  = (const float*)d_in[5];
    float* out = (float*)d_out;

    hipLaunchKernelGGL(init_out_kernel, dim3(1), dim3(256), 0, stream, b2, out);
    hipLaunchKernelGGL(gcn_main_kernel, dim3(BATCH * 8), dim3(256), 0, stream,
                       x, adj, W1, b1, W2, out);
}

// Round 3
// 347.065 us; speedup vs baseline: 1.0524x; 1.0524x over previous
//
#include <hip/hip_runtime.h>

#define BATCH 256
#define NNODE 512

typedef float floatx4 __attribute__((ext_vector_type(4)));

__global__ void init_out_kernel(const float* __restrict__ b2, float* __restrict__ out) {
    int i = blockIdx.x * blockDim.x + threadIdx.x;
    if (i < BATCH) out[i] = (float)NNODE * b2[0];
}

// grid: BATCH*8 blocks, 256 threads. Block (b, chunk) handles rows [chunk*64, chunk*64+64).
// Wave handles 16 rows: quarter-wave `sub` owns rows row0..row0+3 held in register
// accumulators; 16 lanes per row (l), lane reads float4 at c=l+k*16 -> 256B
// contiguous per quarter-wave. xv0/xv1 LDS reads reused across the 4 rows (4x
// fewer ds_read_b128 than R1), all 32 loads/lane in one unrolled loop (MLP),
// and the 4 shuffle-reduce chains are independent (ILP) and run once per wave.
__global__ __launch_bounds__(256, 4) void gcn_main_kernel(
    const float* __restrict__ x,    // [B,N,2]
    const float* __restrict__ adj,  // [B,N,N]
    const float* __restrict__ W1,   // [2,4]
    const float* __restrict__ b1,   // [4]
    const float* __restrict__ W2,   // [4,1]
    float* __restrict__ out)        // [B]
{
    __shared__ __align__(16) float sx0[NNODE];
    __shared__ __align__(16) float sx1[NNODE];
    __shared__ float swsum[4];

    const int b     = blockIdx.x >> 3;
    const int chunk = blockIdx.x & 7;
    const int t     = threadIdx.x;

    // Stage node features: 1024 floats = 256 float4, deinterleave [m][2] -> x0[],x1[]
    {
        const float4 v = ((const float4*)(x + (size_t)b * NNODE * 2))[t];
        const int m = 2 * t;
        sx0[m]     = v.x; sx1[m]     = v.y;
        sx0[m + 1] = v.z; sx1[m + 1] = v.w;
    }

    // Uniform weights into registers
    float w1[8], bb1[4], w2[4];
#pragma unroll
    for (int j = 0; j < 8; ++j) w1[j] = W1[j];
#pragma unroll
    for (int j = 0; j < 4; ++j) { bb1[j] = b1[j]; w2[j] = W2[j]; }

    __syncthreads();

    const int wave = t >> 6;
    const int lane = t & 63;
    const int sub  = lane >> 4;   // quarter-wave: owns 4 consecutive rows
    const int l    = lane & 15;   // column chunk within row

    const int row0 = chunk * 64 + wave * 16 + sub * 4;
    const floatx4* __restrict__ arow =
        (const floatx4*)(adj + ((size_t)b * NNODE + row0) * NNODE);

    float s0[4] = {0.f, 0.f, 0.f, 0.f};
    float s1[4] = {0.f, 0.f, 0.f, 0.f};

#pragma unroll
    for (int k = 0; k < 8; ++k) {
        const int c = l + k * 16;                    // float4 index within row
        const floatx4 xv0 = ((const floatx4*)sx0)[c];
        const floatx4 xv1 = ((const floatx4*)sx1)[c];
#pragma unroll
        for (int r = 0; r < 4; ++r) {
            const floatx4 av = __builtin_nontemporal_load(&arow[(size_t)r * (NNODE / 4) + c]);
            s0[r] += av.x * xv0.x + av.y * xv0.y + av.z * xv0.z + av.w * xv0.w;
            s1[r] += av.x * xv1.x + av.y * xv1.y + av.z * xv1.z + av.w * xv1.w;
        }
    }

    // Four independent 16-lane xor-reduce chains (bits 0-3 stay within quarter-wave)
#pragma unroll
    for (int m = 1; m < 16; m <<= 1) {
#pragma unroll
        for (int r = 0; r < 4; ++r) {
            s0[r] += __shfl_xor(s0[r], m, 64);
            s1[r] += __shfl_xor(s1[r], m, 64);
        }
    }

    // Tiny MLP per row; one representative lane per quarter-wave contributes
    float acc = 0.0f;
    if (l == 0) {
#pragma unroll
        for (int r = 0; r < 4; ++r) {
            float p = 0.0f;
#pragma unroll
            for (int j = 0; j < 4; ++j) {
                float h = fmaf(s0[r], w1[j], fmaf(s1[r], w1[4 + j], bb1[j]));
                h = fmaxf(h, 0.0f);
                p += h * w2[j];
            }
            acc += p;
        }
    }

    // Wave-level then block-level reduction, one atomic per block
#pragma unroll
    for (int m = 1; m < 64; m <<= 1) acc += __shfl_xor(acc, m, 64);
    if (lane == 0) swsum[wave] = acc;
    __syncthreads();
    if (t == 0) {
        atomicAdd(out + b, swsum[0] + swsum[1] + swsum[2] + swsum[3]);
    }
}

extern "C" void kernel_launch(void* const* d_in, const int* in_sizes, int n_in,
                              void* d_out, int out_size, void* d_ws, size_t ws_size,
                              hipStream_t stream) {
    const float* x   = (const float*)d_in[0];
    const float* adj = (const float*)d_in[1];
    const float* W1  = (const float*)d_in[2];
    const float* b1  = (const float*)d_in[3];
    const float* W2  = (const float*)d_in[4];
    const float* b2  = (const float*)d_in[5];
    float* out = (float*)d_out;

    hipLaunchKernelGGL(init_out_kernel, dim3(1), dim3(256), 0, stream, b2, out);
    hipLaunchKernelGGL(gcn_main_kernel, dim3(BATCH * 8), dim3(256), 0, stream,
                       x, adj, W1, b1, W2, out);
}

// Round 4
// 342.808 us; speedup vs baseline: 1.0655x; 1.0124x over previous
//
#include <hip/hip_runtime.h>

#define BATCH 256
#define NNODE 512
#define RPW 16   // rows per wave

typedef float floatx4 __attribute__((ext_vector_type(4)));

__global__ void init_out_kernel(const float* __restrict__ b2, float* __restrict__ out) {
    int i = blockIdx.x * blockDim.x + threadIdx.x;
    if (i < BATCH) out[i] = (float)NNODE * b2[0];
}

// grid: BATCH*8 blocks, 256 threads (4 waves). Block (b,chunk) -> rows [chunk*64, +64).
// Wave w streams 16 consecutive rows; lane l reads float4 cols c0=l and c1=l+64,
// so every wave-load is ONE contiguous 1KB segment (m13 copy pattern). The x
// fragments for (c0,c1) are row-invariant -> hoisted to 16 registers before the
// loop: the hot loop is pure global_load_dwordx4 + FMA, no LDS, no shuffles.
// Per-row 64-lane butterfly reduction afterwards (independent chains, ~tiny vs
// the 32KB/wave memory time).
__global__ __launch_bounds__(256, 4) void gcn_main_kernel(
    const float* __restrict__ x,    // [B,N,2]
    const float* __restrict__ adj,  // [B,N,N]
    const float* __restrict__ W1,   // [2,4]
    const float* __restrict__ b1,   // [4]
    const float* __restrict__ W2,   // [4,1]
    float* __restrict__ out)        // [B]
{
    __shared__ __align__(16) float sx0[NNODE];
    __shared__ __align__(16) float sx1[NNODE];
    __shared__ float swsum[4];

    const int b     = blockIdx.x >> 3;
    const int chunk = blockIdx.x & 7;
    const int t     = threadIdx.x;

    // Stage node features once: deinterleave [m][2] -> sx0[], sx1[]
    {
        const float4 v = ((const float4*)(x + (size_t)b * NNODE * 2))[t];
        const int m = 2 * t;
        sx0[m]     = v.x; sx1[m]     = v.y;
        sx0[m + 1] = v.z; sx1[m + 1] = v.w;
    }

    float w1[8], bb1[4], w2[4];
#pragma unroll
    for (int j = 0; j < 8; ++j) w1[j] = W1[j];
#pragma unroll
    for (int j = 0; j < 4; ++j) { bb1[j] = b1[j]; w2[j] = W2[j]; }

    __syncthreads();

    const int wave = t >> 6;
    const int lane = t & 63;

    // Row-invariant x fragments -> registers (16 floats), LDS done after this.
    const floatx4* sx0v = (const floatx4*)sx0;
    const floatx4* sx1v = (const floatx4*)sx1;
    const int c0 = lane, c1 = lane + 64;
    const floatx4 x0a = sx0v[c0], x1a = sx1v[c0];
    const floatx4 x0b = sx0v[c1], x1b = sx1v[c1];

    const int row0 = chunk * 64 + wave * RPW;
    const floatx4* __restrict__ arow =
        (const floatx4*)(adj + ((size_t)b * NNODE + row0) * NNODE);

    float s0[RPW], s1[RPW];
#pragma unroll
    for (int r = 0; r < RPW; ++r) {
        const floatx4 a0 = __builtin_nontemporal_load(&arow[(size_t)r * (NNODE / 4) + c0]);
        const floatx4 a1 = __builtin_nontemporal_load(&arow[(size_t)r * (NNODE / 4) + c1]);
        s0[r] = a0.x * x0a.x + a0.y * x0a.y + a0.z * x0a.z + a0.w * x0a.w
              + a1.x * x0b.x + a1.y * x0b.y + a1.z * x0b.z + a1.w * x0b.w;
        s1[r] = a0.x * x1a.x + a0.y * x1a.y + a0.z * x1a.z + a0.w * x1a.w
              + a1.x * x1b.x + a1.y * x1b.y + a1.z * x1b.z + a1.w * x1b.w;
    }

    // Butterfly-reduce each row over all 64 lanes (independent chains, ILP).
#pragma unroll
    for (int m = 1; m < 64; m <<= 1) {
#pragma unroll
        for (int r = 0; r < RPW; ++r) {
            s0[r] += __shfl_xor(s0[r], m, 64);
            s1[r] += __shfl_xor(s1[r], m, 64);
        }
    }

    // Tiny MLP per row (uniform across lanes after butterfly; no divergence).
    float acc = 0.0f;
#pragma unroll
    for (int r = 0; r < RPW; ++r) {
        float p = 0.0f;
#pragma unroll
        for (int j = 0; j < 4; ++j) {
            float h = fmaf(s0[r], w1[j], fmaf(s1[r], w1[4 + j], bb1[j]));
            h = fmaxf(h, 0.0f);
            p = fmaf(h, w2[j], p);
        }
        acc += p;
    }

    if (lane == 0) swsum[wave] = acc;
    __syncthreads();
    if (t == 0) {
        atomicAdd(out + b, swsum[0] + swsum[1] + swsum[2] + swsum[3]);
    }
}

extern "C" void kernel_launch(void* const* d_in, const int* in_sizes, int n_in,
                              void* d_out, int out_size, void* d_ws, size_t ws_size,
                              hipStream_t stream) {
    const float* x   = (const float*)d_in[0];
    const float* adj = (const float*)d_in[1];
    const float* W1  = (const float*)d_in[2];
    const float* b1  = (const float*)d_in[3];
    const float* W2  = (const float*)d_in[4];
    const float* b2  = (const float*)d_in[5];
    float* out = (float*)d_out;

    hipLaunchKernelGGL(init_out_kernel, dim3(1), dim3(256), 0, stream, b2, out);
    hipLaunchKernelGGL(gcn_main_kernel, dim3(BATCH * 8), dim3(256), 0, stream,
                       x, adj, W1, b1, W2, out);
}